// Round 1
// baseline (935.884 us; speedup 1.0000x reference)
//
#include <hip/hip_runtime.h>
#include <stdint.h>

// Problem constants (setup_inputs is fixed: S=96, B=2, N=200000, C=67, D=32, K=128)
#define S_   96
#define P_   98            // S+2 padded grid
#define NB_  2             // batch slabs
#define GSZ  (NB_*P_*P_*P_)   // 1,882,384 cells (batches 0..1 only; parked slab never touched)
#define C_   67
#define D_   32
#define KTOP 128

typedef unsigned int u32;
typedef unsigned long long u64;

struct Ctrl {
  u64 prefix;    // radix-select prefix -> final = exact 128th-largest key
  int n_peaks;
  int kk;        // remaining rank within current prefix class
  int selctr;
  int pad;
};

__device__ __forceinline__ int cell4(int b, int x, int y, int z) {
  return ((b*P_ + x + 1)*P_ + y + 1)*P_ + z + 1;
}

__global__ void k_init(Ctrl* c) {
  c->prefix = 0ull; c->n_peaks = 0; c->kk = KTOP; c->selctr = 0;
}

// keys + occupancy + voxel grid
__global__ __launch_bounds__(256) void k_key(const int* __restrict__ vc, const float* __restrict__ offs,
                                             int* __restrict__ keyA, int* __restrict__ rank,
                                             int* __restrict__ vgrid, int N) {
  int i = blockIdx.x*256 + threadIdx.x;
  if (i >= N) return;
  const int4 q = ((const int4*)vc)[i];
  int ox = (int)offs[3*i], oy = (int)offs[3*i+1], oz = (int)offs[3*i+2];
  int k = cell4(q.x, q.y+ox, q.z+oy, q.w+oz);
  keyA[i] = k;
  rank[k] = 1;                                // occupancy (scanned in place later)
  vgrid[cell4(q.x, q.y, q.z, q.w)] = i;       // coords unique -> no race
}

// ---- exclusive scan over GSZ ints (3 kernels) ----
#define SC_TPB 256
#define SC_EPT 8
#define SC_EPB (SC_TPB*SC_EPT)

__global__ __launch_bounds__(SC_TPB) void k_scan1(int* __restrict__ a, int* __restrict__ bsum, int n) {
  __shared__ int sd[SC_TPB];
  int t = threadIdx.x;
  int base = blockIdx.x*SC_EPB + t*SC_EPT;
  int x[SC_EPT]; int s = 0;
  #pragma unroll
  for (int e = 0; e < SC_EPT; ++e) { int idx = base+e; x[e] = (idx < n) ? a[idx] : 0; s += x[e]; }
  sd[t] = s; __syncthreads();
  for (int off = 1; off < SC_TPB; off <<= 1) {
    int v = (t >= off) ? sd[t-off] : 0; __syncthreads(); sd[t] += v; __syncthreads();
  }
  int run = sd[t] - s;   // exclusive
  #pragma unroll
  for (int e = 0; e < SC_EPT; ++e) { int idx = base+e; if (idx < n) a[idx] = run; run += x[e]; }
  if (t == SC_TPB-1) bsum[blockIdx.x] = sd[t];
}

__global__ __launch_bounds__(SC_TPB) void k_scan2(int* __restrict__ bsum, int nb) {
  __shared__ int sd[SC_TPB];
  int t = threadIdx.x;
  int x[4]; int s = 0;
  #pragma unroll
  for (int e = 0; e < 4; ++e) { int idx = t*4+e; x[e] = (idx < nb) ? bsum[idx] : 0; s += x[e]; }
  sd[t] = s; __syncthreads();
  for (int off = 1; off < SC_TPB; off <<= 1) {
    int v = (t >= off) ? sd[t-off] : 0; __syncthreads(); sd[t] += v; __syncthreads();
  }
  int run = sd[t] - s;
  #pragma unroll
  for (int e = 0; e < 4; ++e) { int idx = t*4+e; if (idx < nb) bsum[idx] = run; run += x[e]; }
}

__global__ __launch_bounds__(SC_TPB) void k_scan3(int* __restrict__ a, const int* __restrict__ bsum, int n) {
  int add = bsum[blockIdx.x];
  int base = blockIdx.x*SC_EPB + threadIdx.x*SC_EPT;
  #pragma unroll
  for (int e = 0; e < SC_EPT; ++e) { int idx = base+e; if (idx < n) a[idx] += add; }
}

// seg = rank of key among sorted unique keys; counts; cluster grid; sid->cell map
__global__ __launch_bounds__(256) void k_seg(const int* __restrict__ keyA, const int* __restrict__ rank,
                                             int* __restrict__ seg, int* __restrict__ cnts,
                                             int* __restrict__ cgrid, int* __restrict__ ckey, int N) {
  int i = blockIdx.x*256 + threadIdx.x;
  if (i >= N) return;
  int k = keyA[i];
  int s = rank[k];
  seg[i] = s;
  atomicAdd(&cnts[s], 1);
  cgrid[k] = s;   // duplicates write same value
  ckey[s] = k;
}

__global__ __launch_bounds__(256) void k_accum(const int* __restrict__ seg, const float* __restrict__ feats,
                                               float* __restrict__ clussum, int total) {
  int idx = blockIdx.x*256 + threadIdx.x;
  if (idx >= total) return;
  int i = idx / C_;
  int c = idx - i*C_;
  atomicAdd(&clussum[(size_t)seg[i]*C_ + c], feats[idx]);
}

__global__ __launch_bounds__(256) void k_fab(const int* __restrict__ seg, const int* __restrict__ cnts,
                                             const float* __restrict__ cent, float* __restrict__ fab, int N) {
  int i = blockIdx.x*256 + threadIdx.x;
  if (i >= N) return;
  fab[2*i]   = cent[i];
  fab[2*i+1] = (float)cnts[seg[i]];
}

// wave-per-segment 3x3x3 average pool over cluster cells
__global__ __launch_bounds__(64) void k_pool(const int* __restrict__ cnts, const int* __restrict__ ckey,
                                             const int* __restrict__ cgrid, const float* __restrict__ clussum,
                                             float* __restrict__ pooled, int N) {
  int s = blockIdx.x;
  if (cnts[s] == 0) return;
  __shared__ int jj[27]; __shared__ float w[27];
  int t = threadIdx.x;
  if (t < 27) {
    int dx = t/9 - 1, dy = (t/3)%3 - 1, dz = t%3 - 1;
    int j = cgrid[ckey[s] + (dx*P_ + dy)*P_ + dz];
    jj[t] = j;
    w[t]  = (j >= 0) ? 1.f/(float)cnts[j] : 0.f;   // clussum is raw sum; x1/count = cluster mean
  }
  __syncthreads();
  int cnt = 0;
  #pragma unroll
  for (int k = 0; k < 27; ++k) cnt += (jj[k] >= 0) ? 1 : 0;
  for (int c = t; c < C_; c += 64) {
    float a = 0.f;
    #pragma unroll
    for (int k = 0; k < 27; ++k) { int j = jj[k]; if (j >= 0) a += clussum[(size_t)j*C_ + c]*w[k]; }
    pooled[(size_t)s*C_ + c] = a/(float)cnt;
  }
}

// U[g] = relu(pooled[seg[g]] @ W_desc), for g in [0, n_unique) (guard: cnts[g]>0)
__global__ __launch_bounds__(256) void k_U(const int* __restrict__ seg, const int* __restrict__ cnts,
                                           const float* __restrict__ pooled, const float* __restrict__ Wd,
                                           float* __restrict__ U, int N) {
  int idx = blockIdx.x*256 + threadIdx.x;
  int g = idx >> 5, d = idx & 31;
  if (g >= N) return;
  if (cnts[g] == 0) return;
  int s = seg[g];
  const float* pr = pooled + (size_t)s*C_;
  float acc = 0.f;
  for (int c = 0; c < C_; ++c) acc += pr[c]*Wd[c*D_ + d];
  U[(size_t)g*D_ + d] = fmaxf(acc, 0.f);
}

__global__ __launch_bounds__(256) void k_mixer(const int* __restrict__ vc, const int* __restrict__ vgrid,
                                               const float* __restrict__ fab, const float* __restrict__ mW,
                                               const float* __restrict__ mB, float* __restrict__ out, int N) {
  int i = blockIdx.x*256 + threadIdx.x;
  if (i >= N) return;
  const int4 q = ((const int4*)vc)[i];
  int bc = cell4(q.x, q.y, q.z, q.w);
  float mix = mB[0];
  #pragma unroll
  for (int k = 0; k < 27; ++k) {
    int dx = k/9 - 1, dy = (k/3)%3 - 1, dz = k%3 - 1;
    int j = vgrid[bc + (dx*P_ + dy)*P_ + dz];
    if (j >= 0) mix += fab[2*j]*mW[2*k] + fab[2*j+1]*mW[2*k+1];
  }
  out[i] = 1.f/(1.f + expf(-mix));
}

__global__ __launch_bounds__(256) void k_peak(const int* __restrict__ vc, const int* __restrict__ vgrid,
                                              const float* __restrict__ out, Ctrl* __restrict__ ctrl,
                                              u64* __restrict__ cand, int N) {
  int i = blockIdx.x*256 + threadIdx.x;
  if (i >= N) return;
  const float NINF = __int_as_float(0xff800000);
  float sc = out[i];
  bool m = sc > 0.1f;
  const int4 q = ((const int4*)vc)[i];
  int bc = cell4(q.x, q.y, q.z, q.w);
  float hmax = NINF;
  #pragma unroll
  for (int k = 0; k < 27; ++k) {
    int dx = k/9 - 1, dy = (k/3)%3 - 1, dz = k%3 - 1;
    int j = vgrid[bc + (dx*P_ + dy)*P_ + dz];
    if (j >= 0) { float sj = out[j]; float vj = (sj > 0.1f) ? sj : NINF; hmax = fmaxf(hmax, vj); }
  }
  if (m && hmax == sc && sc > 0.2f) {
    int pos = atomicAdd(&ctrl->n_peaks, 1);
    cand[pos] = ((u64)__float_as_uint(sc) << 32) | (u32)(~(u32)i);   // value desc, index asc
  }
}

__global__ __launch_bounds__(256) void k_hist(const u64* __restrict__ cand, const Ctrl* __restrict__ ctrl,
                                              int* __restrict__ hist, int shift) {
  int idx = blockIdx.x*256 + threadIdx.x;
  if (idx >= ctrl->n_peaks) return;
  u64 key = cand[idx];
  if (shift != 48 && (((key ^ ctrl->prefix) >> (shift + 16)) != 0)) return;
  atomicAdd(&hist[(int)((key >> shift) & 0xFFFF)], 1);
}

__global__ __launch_bounds__(256) void k_scansel(int* __restrict__ hist, Ctrl* __restrict__ ctrl, int shift) {
  __shared__ int sd[256];
  int t = threadIdx.x;
  int kk = ctrl->kk;                 // read before any thread can update (barrier below orders it)
  int lo = 65536 - (t+1)*256;        // chunk t covers descending bucket range
  int s = 0;
  for (int b = lo; b < lo+256; ++b) s += hist[b];
  sd[t] = s; __syncthreads();
  for (int off = 1; off < 256; off <<= 1) {
    int v = (t >= off) ? sd[t-off] : 0; __syncthreads(); sd[t] += v; __syncthreads();
  }
  int before = sd[t] - s;            // count in buckets above my chunk
  if (before < kk && before + s >= kk) {
    int cum = before;
    for (int b = lo+255; b >= lo; --b) {
      int h = hist[b];
      if (cum + h >= kk) { ctrl->prefix |= ((u64)(u32)b) << shift; ctrl->kk = kk - cum; break; }
      cum += h;
    }
  }
  __syncthreads();
  for (int b = lo; b < lo+256; ++b) hist[b] = 0;   // ready for next pass
}

__global__ __launch_bounds__(256) void k_collect(const u64* __restrict__ cand, Ctrl* __restrict__ ctrl,
                                                 u64* __restrict__ sel) {
  int idx = blockIdx.x*256 + threadIdx.x;
  int np = ctrl->n_peaks;
  if (idx >= np) return;
  u64 key = cand[idx];
  bool take = (np <= KTOP) ? true : (key >= ctrl->prefix);
  if (take) { int pos = atomicAdd(&ctrl->selctr, 1); if (pos < KTOP) sel[pos] = key; }
}

__global__ void k_rank(const u64* __restrict__ sel, const Ctrl* __restrict__ ctrl,
                       float* __restrict__ out, int* __restrict__ topidx, int N) {
  __shared__ u64 sk[KTOP];
  int t = threadIdx.x;
  int ns = ctrl->selctr; if (ns > KTOP) ns = KTOP;
  out[N + t] = 0.f;
  topidx[t] = -1;
  sk[t] = (t < ns) ? sel[t] : 0ull;
  __syncthreads();
  if (t < ns) {
    u64 my = sk[t];
    int r = 0;
    for (int mI = 0; mI < KTOP; ++mI) r += (mI < ns && sk[mI] > my) ? 1 : 0;
    out[N + r]  = __uint_as_float((u32)(my >> 32));
    topidx[r]   = (int)~(u32)(my & 0xFFFFFFFFull);
  }
}

// descriptors: row 0 = bg; row 1+r = conf_r * relu(pooled[seg[idx_r]] @ W_desc)
__global__ void k_desc(const int* __restrict__ topidx, const int* __restrict__ seg,
                       const float* __restrict__ pooled, const float* __restrict__ Wd,
                       const float* __restrict__ bg, const float* __restrict__ outc,
                       float* __restrict__ descg, int N) {
  int b = blockIdx.x; int d = threadIdx.x;
  if (b == 0) { descg[d] = bg[d]; return; }
  int r = b - 1;
  int ti = topidx[r];
  float v = 0.f;
  if (ti >= 0) {
    int s = seg[ti];
    float cf = outc[N + r];
    const float* pr = pooled + (size_t)s*C_;
    float acc = 0.f;
    for (int c = 0; c < C_; ++c) acc += pr[c]*Wd[c*D_ + d];
    v = cf*fmaxf(acc, 0.f);
  }
  descg[b*D_ + d] = v;
}

// instance[i][j] = U[seg[i]] . descriptors[j]  — register-blocked [N,32]x[32,129]
#define VPB 32
__global__ __launch_bounds__(256) void k_inst(const int* __restrict__ seg, const float* __restrict__ Ub,
                                              const float* __restrict__ descg, float* __restrict__ out, int N) {
  __shared__ __align__(16) float ds[129*36];   // stride 36: float4-aligned, conflict-free
  __shared__ __align__(16) float us[VPB*36];
  __shared__ int gs[VPB];
  int tid = threadIdx.x;
  for (int idx = tid; idx < 129*D_; idx += 256) { int j = idx >> 5, d = idx & 31; ds[j*36 + d] = descg[idx]; }
  int v0 = blockIdx.x*VPB;
  if (tid < VPB) { int v = v0 + tid; gs[tid] = (v < N) ? seg[v] : -1; }
  __syncthreads();
  for (int idx = tid; idx < VPB*D_; idx += 256) {
    int v = idx >> 5, d = idx & 31; int g = gs[v];
    us[v*36 + d] = (g >= 0) ? Ub[(size_t)g*D_ + d] : 0.f;
  }
  __syncthreads();
  int tx = tid & 31, ty = tid >> 5;          // 4 voxels x 4 cols per thread
  const float* usb = us + ty*4*36;
  float acc[4][4];
  #pragma unroll
  for (int a = 0; a < 4; ++a)
    #pragma unroll
    for (int b = 0; b < 4; ++b) acc[a][b] = 0.f;
  float a128[4] = {0.f, 0.f, 0.f, 0.f};
  #pragma unroll
  for (int d4 = 0; d4 < 8; ++d4) {
    float4 uv[4];
    #pragma unroll
    for (int k = 0; k < 4; ++k) uv[k] = *(const float4*)(usb + k*36 + d4*4);
    #pragma unroll
    for (int r = 0; r < 4; ++r) {
      float4 dv = *(const float4*)(ds + (tx + 32*r)*36 + d4*4);
      #pragma unroll
      for (int k = 0; k < 4; ++k)
        acc[k][r] += uv[k].x*dv.x + uv[k].y*dv.y + uv[k].z*dv.z + uv[k].w*dv.w;
    }
    if (tx == 0) {
      float4 dv = *(const float4*)(ds + 128*36 + d4*4);
      #pragma unroll
      for (int k = 0; k < 4; ++k)
        a128[k] += uv[k].x*dv.x + uv[k].y*dv.y + uv[k].z*dv.z + uv[k].w*dv.w;
    }
  }
  #pragma unroll
  for (int k = 0; k < 4; ++k) {
    int v = v0 + ty*4 + k;
    if (v < N) {
      float* o = out + (size_t)v*129;
      #pragma unroll
      for (int r = 0; r < 4; ++r) o[tx + 32*r] = acc[k][r];
      if (tx == 0) o[128] = a128[k];
    }
  }
}

extern "C" void kernel_launch(void* const* d_in, const int* in_sizes, int n_in,
                              void* d_out, int out_size, void* d_ws, size_t ws_size,
                              hipStream_t stream) {
  const int*   vc    = (const int*)d_in[0];
  const float* feats = (const float*)d_in[1];
  const float* cent  = (const float*)d_in[2];
  const float* offs  = (const float*)d_in[3];
  const float* bg    = (const float*)d_in[4];
  const float* Wd    = (const float*)d_in[5];
  const float* mW    = (const float*)d_in[6];
  const float* mB    = (const float*)d_in[7];
  int N = in_sizes[2];

  float* out = (float*)d_out;   // [0,N) refined | [N,N+128) conf | [N+128, ...) instance [N,129]

  // ---- workspace carve (≈162 MB) ----
  uint8_t* base = (uint8_t*)d_ws;
  size_t off = 0;
  auto carve = [&](size_t bytes) -> void* {
    off = (off + 255) & ~(size_t)255;
    void* r = base + off; off += bytes; return r;
  };
  Ctrl*  ctrl    = (Ctrl*) carve(sizeof(Ctrl));
  int*   keyA    = (int*)  carve((size_t)N*4);
  int*   seg     = (int*)  carve((size_t)N*4);
  int*   cnts    = (int*)  carve((size_t)N*4);
  int*   ckey    = (int*)  carve((size_t)N*4);
  float* fab     = (float*)carve((size_t)N*8);
  int*   rank    = (int*)  carve((size_t)GSZ*4);
  int*   bsum    = (int*)  carve(1024*4);
  int*   cgrid   = (int*)  carve((size_t)GSZ*4);
  int*   vgrid   = (int*)  carve((size_t)GSZ*4);
  float* clussum = (float*)carve((size_t)N*C_*4);
  float* pooled  = (float*)carve((size_t)N*C_*4);
  float* U       = (float*)carve((size_t)N*D_*4);
  u64*   cand    = (u64*)  carve((size_t)N*8);
  int*   hist    = (int*)  carve(65536*4);
  u64*   sel     = (u64*)  carve(KTOP*8);
  int*   topidx  = (int*)  carve(KTOP*4);
  float* descg   = (float*)carve(129*D_*4);

  int nb256 = (N + 255)/256;
  int nscan = (GSZ + SC_EPB - 1)/SC_EPB;

  // init
  hipMemsetAsync(rank,   0x00, (size_t)GSZ*4, stream);
  hipMemsetAsync(cgrid,  0xFF, (size_t)GSZ*4, stream);
  hipMemsetAsync(vgrid,  0xFF, (size_t)GSZ*4, stream);
  hipMemsetAsync(cnts,   0x00, (size_t)N*4, stream);
  hipMemsetAsync(clussum,0x00, (size_t)N*C_*4, stream);
  hipMemsetAsync(hist,   0x00, 65536*4, stream);
  k_init<<<1, 1, 0, stream>>>(ctrl);

  // revoxelize: keys, occupancy, voxel grid; rank = exclusive scan of occupancy
  k_key<<<nb256, 256, 0, stream>>>(vc, offs, keyA, rank, vgrid, N);
  k_scan1<<<nscan, SC_TPB, 0, stream>>>(rank, bsum, GSZ);
  k_scan2<<<1, SC_TPB, 0, stream>>>(bsum, nscan);
  k_scan3<<<nscan, SC_TPB, 0, stream>>>(rank, bsum, GSZ);
  k_seg<<<nb256, 256, 0, stream>>>(keyA, rank, seg, cnts, cgrid, ckey, N);

  // cluster features + pooling
  int totNC = N*C_;
  k_accum<<<(totNC + 255)/256, 256, 0, stream>>>(seg, feats, clussum, totNC);
  k_fab<<<nb256, 256, 0, stream>>>(seg, cnts, cent, fab, N);
  k_pool<<<N, 64, 0, stream>>>(cnts, ckey, cgrid, clussum, pooled, N);
  k_U<<<(N*D_ + 255)/256, 256, 0, stream>>>(seg, cnts, pooled, Wd, U, N);

  // mixer + sigmoid (output 0), then peaks
  k_mixer<<<nb256, 256, 0, stream>>>(vc, vgrid, fab, mW, mB, out, N);
  k_peak<<<nb256, 256, 0, stream>>>(vc, vgrid, out, ctrl, cand, N);

  // exact top-128 radix select on 64-bit (score, ~idx) keys
  for (int shift = 48; shift >= 0; shift -= 16) {
    k_hist<<<nb256, 256, 0, stream>>>(cand, ctrl, hist, shift);
    k_scansel<<<1, 256, 0, stream>>>(hist, ctrl, shift);
  }
  k_collect<<<nb256, 256, 0, stream>>>(cand, ctrl, sel);
  k_rank<<<1, KTOP, 0, stream>>>(sel, ctrl, out, topidx, N);   // conf (output 1) + indices

  // descriptors + instance logits (output 2)
  k_desc<<<KTOP + 1, D_, 0, stream>>>(topidx, seg, pooled, Wd, bg, out, descg, N);
  k_inst<<<(N + VPB - 1)/VPB, 256, 0, stream>>>(seg, U, descg, out + N + KTOP, N);
}